// Round 12
// baseline (176.758 us; speedup 1.0000x reference)
//
#include <hip/hip_runtime.h>
#include <hip/hip_bf16.h>

// Problem constants
#define B_  2
#define S_  2048
#define D_  1024
#define H_  16
#define DH_ 64
#define M_  (B_*S_)   // 4096 rows
#define KSTR 2048

typedef unsigned short ushort_t;
typedef __attribute__((ext_vector_type(8)))  short bf16x8;
typedef __attribute__((ext_vector_type(8)))  _Float16 f16x8;
typedef __attribute__((ext_vector_type(4)))  float f32x4;
typedef __attribute__((ext_vector_type(16))) float f32x16;
typedef __attribute__((ext_vector_type(4)))  int   i32x4;

#define MFMA16x16(A,Bb,C) __builtin_amdgcn_mfma_f32_16x16x32_bf16(A,Bb,C,0,0,0)
#define MFMA32(A,Bb,C)    __builtin_amdgcn_mfma_f32_32x32x16_bf16(A,Bb,C,0,0,0)
#define QSCALE 0.18033688011112042f   // (1/sqrt(64)) * log2(e)

__device__ __forceinline__ ushort_t f2bf(float f) {
    return __builtin_bit_cast(ushort_t, __float2bfloat16(f));
}
__device__ __forceinline__ unsigned pack2(float a, float b) {
    return (unsigned)f2bf(a) | ((unsigned)f2bf(b) << 16);
}

// async global->LDS, 16B per lane; LDS dest = wave-uniform base + lane*16
__device__ __forceinline__ void gll16(const void* g, void* l) {
    __builtin_amdgcn_global_load_lds(
        (const __attribute__((address_space(1))) unsigned int*)g,
        (__attribute__((address_space(3))) unsigned int*)l, 16, 0, 0);
}

// chunk-XOR swizzle: 16B chunk c8 of row -> physical short offset.
#define SWZ(row, c8) ((((c8) ^ ((row) & 7))) * 8)

// ---------------------------------------------------------------------------
// Prep: mask expansion (bool8 vs int32 auto-detect) + fused KV bias build.
// ---------------------------------------------------------------------------
__global__ void prep_kernel(const unsigned char* __restrict__ mask_raw,
                            float* __restrict__ mf,
                            const float* __restrict__ bk,
                            const float* __restrict__ bv,
                            float* __restrict__ biasKV) {
    __shared__ int isBool;
    int tid = threadIdx.x;
    if (tid == 0) isBool = 0;
    __syncthreads();
    int found = 0;
    for (int i = tid; i < M_; i += 256) {
        if ((i & 3) != 0 && mask_raw[i] != 0) found = 1;
    }
    if (found) atomicOr(&isBool, 1);
    __syncthreads();
    const int isb = isBool;
    for (int i = tid; i < M_; i += 256) {
        int m;
        if (isb) m = (mask_raw[i] != 0);
        else     m = (((const int*)mask_raw)[i] != 0);
        mf[i] = m ? 1.0f : 0.0f;
    }
    for (int i = tid; i < D_; i += 256) {
        biasKV[i]      = bk[i];
        biasKV[D_ + i] = bv[i];
    }
}

// ---------------------------------------------------------------------------
// f32 -> bf16 convert, both activations in one launch
// ---------------------------------------------------------------------------
__global__ __launch_bounds__(256) void cvt_bf16_2(const float* __restrict__ x,
                                                  const float* __restrict__ mem,
                                                  ushort_t* __restrict__ xb,
                                                  ushort_t* __restrict__ mb) {
    const int i = blockIdx.x * 256 + threadIdx.x;
    const float* src = blockIdx.y ? mem : x;
    ushort_t*    dst = blockIdx.y ? mb  : xb;
    float4 a = *(const float4*)(src + (size_t)i * 8);
    float4 b = *(const float4*)(src + (size_t)i * 8 + 4);
    bf16x8 t;
    t[0] = (short)f2bf(a.x); t[1] = (short)f2bf(a.y);
    t[2] = (short)f2bf(a.z); t[3] = (short)f2bf(a.w);
    t[4] = (short)f2bf(b.x); t[5] = (short)f2bf(b.y);
    t[6] = (short)f2bf(b.z); t[7] = (short)f2bf(b.w);
    *(bf16x8*)(dst + (size_t)i * 8) = t;
}

// ---------------------------------------------------------------------------
// W[k][n] f32 -> Wt[n][k] bf16, all four weights in one launch (blockIdx.z)
// ---------------------------------------------------------------------------
__global__ __launch_bounds__(256) void transpose_cvt4(const float* __restrict__ w0,
                                                      const float* __restrict__ w1,
                                                      const float* __restrict__ w2,
                                                      const float* __restrict__ w3,
                                                      ushort_t* __restrict__ d0,
                                                      ushort_t* __restrict__ d1,
                                                      ushort_t* __restrict__ d2,
                                                      ushort_t* __restrict__ d3) {
    __shared__ ushort_t T[64][65];
    const float* W; ushort_t* Wt;
    switch (blockIdx.z) {
        case 0:  W = w0; Wt = d0; break;
        case 1:  W = w1; Wt = d1; break;
        case 2:  W = w2; Wt = d2; break;
        default: W = w3; Wt = d3; break;
    }
    const int bi = blockIdx.y;
    const int bj = blockIdx.x;
    const int tid = threadIdx.x;
    const int r = tid >> 2;
    const int c = tid & 3;

    const float* src = W + (size_t)(bi * 64 + r) * D_ + bj * 64 + c * 16;
    #pragma unroll
    for (int q = 0; q < 4; q++) {
        float4 v = *(const float4*)(src + q * 4);
        T[r][c * 16 + q * 4 + 0] = f2bf(v.x);
        T[r][c * 16 + q * 4 + 1] = f2bf(v.y);
        T[r][c * 16 + q * 4 + 2] = f2bf(v.z);
        T[r][c * 16 + q * 4 + 3] = f2bf(v.w);
    }
    __syncthreads();
    ushort_t tmp[16];
    #pragma unroll
    for (int q = 0; q < 16; q++) tmp[q] = T[c * 16 + q][r];
    ushort_t* dst = Wt + (size_t)(bj * 64 + r) * D_ + bi * 64 + c * 16;
    *(bf16x8*)(dst)     = *(bf16x8*)&tmp[0];
    *(bf16x8*)(dst + 8) = *(bf16x8*)&tmp[8];
}

// ---------------------------------------------------------------------------
// GEMM body: C = (A[.,1024] @ W + bias) * scale
// 128x128 tile, BK=64, 512 thr = 8 waves (2M x 4N).
// MODE 0: f32 out rowmajor[N]; MODE 1: bf16 out rowmajor[N];
// MODE 2: bf16 out TRANSPOSED per-head -> vtg[(b*16+h)*64+dh][S_]  (V path)
// ---------------------------------------------------------------------------
template<int MODE>
__device__ __forceinline__ void gemm_body(const ushort_t* __restrict__ A,
                                          const ushort_t* __restrict__ Bt,
                                          const float* __restrict__ bias,
                                          void* __restrict__ Cv,
                                          float scale, int N, int bn,
                                          ushort_t* lds) {
    ushort_t (*As)[64] = (ushort_t(*)[64])lds;
    ushort_t (*Bs)[64] = (ushort_t(*)[64])(lds + 8192);

    const int tid = threadIdx.x;
    const int l15 = tid & 15;
    const int g   = (tid & 63) >> 4;
    const int w   = tid >> 6;
    const int wr  = w >> 2;
    const int wc  = w & 3;
    const int bm  = blockIdx.y * 128;

    f32x4 acc[4][2] = {};

    #pragma unroll 1
    for (int kt = 0; kt < D_; kt += 64) {
        __syncthreads();
        #pragma unroll
        for (int j = 0; j < 2; j++) {
            const int idx = tid + 512 * j;
            const int row = idx >> 3;
            const int c8  = idx & 7;
            gll16(A  + (size_t)(bm + row) * D_ + kt + c8 * 8,
                  (char*)&As[0][0] + idx * 16);
            gll16(Bt + (size_t)(bn + row) * D_ + kt + c8 * 8,
                  (char*)&Bs[0][0] + idx * 16);
        }
        __syncthreads();

        #pragma unroll
        for (int kk = 0; kk < 2; kk++) {
            bf16x8 a[4], b[2];
            #pragma unroll
            for (int m = 0; m < 4; m++)
                a[m] = *(bf16x8*)&As[wr * 64 + 16 * m + l15][kk * 32 + g * 8];
            #pragma unroll
            for (int n = 0; n < 2; n++)
                b[n] = *(bf16x8*)&Bs[wc * 32 + 16 * n + l15][kk * 32 + g * 8];
            #pragma unroll
            for (int m = 0; m < 4; m++)
                #pragma unroll
                for (int n = 0; n < 2; n++)
                    acc[m][n] = MFMA16x16(a[m], b[n], acc[m][n]);
        }
    }

    if (MODE != 2) {
        #pragma unroll
        for (int n = 0; n < 2; n++) {
            const int col = bn + wc * 32 + 16 * n + l15;
            const float bv = bias[col];
            #pragma unroll
            for (int m = 0; m < 4; m++) {
                #pragma unroll
                for (int r = 0; r < 4; r++) {
                    const int row = bm + wr * 64 + 16 * m + 4 * g + r;
                    const float val = (acc[m][n][r] + bv) * scale;
                    if (MODE == 1) ((ushort_t*)Cv)[(size_t)row * N + col] = f2bf(val);
                    else           ((float*)Cv)[(size_t)row * N + col] = val;
                }
            }
        }
    } else {
        // V path: transpose tile in LDS, store vtg[(b*16+h)*64+dh][s] coalesced.
        __syncthreads();   // done reading As/Bs
        ushort_t (*T)[136] = (ushort_t(*)[136])lds;
        #pragma unroll
        for (int n = 0; n < 2; n++) {
            const int col_l = wc * 32 + 16 * n + l15;
            const float bv = bias[bn + col_l];
            #pragma unroll
            for (int m = 0; m < 4; m++) {
                #pragma unroll
                for (int r = 0; r < 4; r++) {
                    const int row_l = wr * 64 + 16 * m + 4 * g + r;
                    T[col_l][row_l] = f2bf((acc[m][n][r] + bv) * scale);
                }
            }
        }
        __syncthreads();
        const int tc = tid >> 2;              // 0..127 (local col = output row)
        const int rc = (tid & 3) * 32;        // local row chunk (s-direction)
        const int col1 = bn + tc - 1024;      // 0..1023
        const int hh = col1 >> 6, dh = col1 & 63;
        const int bb = bm >> 11;
        const int s0 = (bm & 2047) + rc;
        ushort_t* dst = (ushort_t*)Cv + ((size_t)(bb * H_ + hh) * DH_ + dh) * S_ + s0;
        #pragma unroll
        for (int c = 0; c < 4; c++)
            *(bf16x8*)(dst + c * 8) = *(const bf16x8*)&T[tc][rc + c * 8];
    }
}

// Q + K + V projections in one dispatch: x = 0..7 -> Q, 8..15 -> K, 16..23 -> V
__global__ __launch_bounds__(512) void gemm_qkv(const ushort_t* __restrict__ xb,
                                                const ushort_t* __restrict__ mb,
                                                const ushort_t* __restrict__ wqT,
                                                const ushort_t* __restrict__ wkvT,
                                                const float* __restrict__ bq,
                                                const float* __restrict__ biasKV,
                                                ushort_t* __restrict__ qb,
                                                ushort_t* __restrict__ kg,
                                                ushort_t* __restrict__ vtg) {
    __shared__ ushort_t lds[17408];   // max(As+Bs = 16384, T = 128*136 = 17408)
    const int x = blockIdx.x;
    if (x < 8)       gemm_body<1>(xb, wqT,  bq,     qb,  QSCALE, D_, x * 128, lds);
    else if (x < 16) gemm_body<1>(mb, wkvT, biasKV, kg,  1.0f,   D_, (x - 8) * 128, lds);
    else             gemm_body<2>(mb, wkvT, biasKV, vtg, 1.0f,   KSTR, 1024 + (x - 16) * 128, lds);
}

// O projection (f32 out)
__global__ __launch_bounds__(512) void gemm_o(const ushort_t* __restrict__ ab,
                                              const ushort_t* __restrict__ woT,
                                              const float* __restrict__ bo,
                                              float* __restrict__ out) {
    __shared__ ushort_t lds[16384];
    gemm_body<0>(ab, woT, bo, out, 1.0f, D_, blockIdx.x * 128, lds);
}

// ---------------------------------------------------------------------------
// MFMA 32x32 flash attention, 2-way KV-split for occupancy (4 waves/SIMD).
// Fixed-max softmax makes split partials ADDITIVE: each split writes f16
// numerators + f32 denominators; combine kernel divides.
// XCD-aware: blk.x = qt*32 + bh  =>  bid%8 = bh%8 for both splits.
// ---------------------------------------------------------------------------
#define KB 64
#define NSPLIT 2
#define NTS (S_ / NSPLIT / KB)   // 16 tiles per split

__device__ __forceinline__ int sx32(unsigned v) {
    return __shfl_xor((int)v, 32);
}

__global__ __launch_bounds__(256) void attn_mfma(const ushort_t* __restrict__ q,
                                                 const ushort_t* __restrict__ kg,
                                                 const ushort_t* __restrict__ vtg,
                                                 const float* __restrict__ maskf,
                                                 _Float16* __restrict__ nbuf,  // [NSPLIT][M_][D_]
                                                 float* __restrict__ dbuf) {   // [NSPLIT][B_*H_][S_]
    __shared__ __attribute__((aligned(16))) ushort_t Ks[2][KB][64];   // 16 KB
    __shared__ __attribute__((aligned(16))) ushort_t Vt[2][DH_][64];  // 16 KB
    __shared__ float melt[2][KB];

    const int tid = threadIdx.x;
    const int w   = tid >> 6;
    const int l31 = tid & 31;
    const int hi  = (tid >> 5) & 1;

    // XCD-aware decode: blk.x = qt*32 + bh   (bh = b*16 + h)
    const int blk = blockIdx.x;
    const int qt  = blk >> 5;
    const int bh  = blk & 31;
    const int h   = bh & 15;
    const int b   = bh >> 4;
    const int z   = blockIdx.y;
    const int kt0 = z * (S_ / NSPLIT);

    const int qr0 = qt * 128 + w * 32;
    const size_t hoff  = (size_t)h * DH_;
    const size_t kbase = (size_t)(b * S_) * D_ + hoff;
    const size_t vbase = (size_t)((b * H_ + h) * DH_) * S_;

    // staging coords: 256 threads x 2 chunks; same decomposition for K and V
    const int srow0 = tid >> 3, sc8 = tid & 7;

    // Q fragments (registers): B-frag col=q=l31, k = ks*16 + hi*8 + e
    bf16x8 qf[4];
    {
        const ushort_t* qp = q + (size_t)(b * S_ + qr0 + l31) * D_ + hoff + hi * 8;
        #pragma unroll
        for (int ks = 0; ks < 4; ks++)
            qf[ks] = *(const bf16x8*)(qp + ks * 16);
    }

    f32x16 oacc0 = {}, oacc1 = {};   // O[q=crow(reg,hi)][dh = l31 / 32+l31]
    float ps = 0.f;                  // partial denominator (lane's keys only)

    bf16x8 kreg[2], vreg[2];
    float  mreg = 0.f;

    // prologue: tile kt0 -> regs -> buf0; tile kt0+KB -> regs
    #pragma unroll
    for (int j = 0; j < 2; j++) {
        kreg[j] = *(const bf16x8*)&kg[kbase + (size_t)(kt0 + srow0 + 32 * j) * D_ + sc8 * 8];
        vreg[j] = *(const bf16x8*)&vtg[vbase + (size_t)(srow0 + 32 * j) * S_ + kt0 + sc8 * 8];
    }
    if (tid < KB) mreg = maskf[b * S_ + kt0 + tid];

    #pragma unroll
    for (int j = 0; j < 2; j++) {
        const int row = srow0 + 32 * j;
        *(bf16x8*)&Ks[0][row][SWZ(row, sc8)] = kreg[j];
        *(bf16x8*)&Vt[0][row][SWZ(row, sc8)] = vreg[j];
    }
    if (tid < KB) melt[0][tid] = 8.0f + 1.0e4f * mreg;

    #pragma unroll
    for (int j = 0; j < 2; j++) {
        kreg[j] = *(const bf16x8*)&kg[kbase + (size_t)(kt0 + KB + srow0 + 32 * j) * D_ + sc8 * 8];
        vreg[j] = *(const bf16x8*)&vtg[vbase + (size_t)(srow0 + 32 * j) * S_ + kt0 + KB + sc8 * 8];
    }
    if (tid < KB) mreg = maskf[b * S_ + kt0 + KB + tid];

    int cur = 0;
    #pragma unroll 1
    for (int t = 0; t < NTS; t++) {
        __syncthreads();   // buf[cur] ready; buf[cur^1] readers done

        if (t + 1 < NTS) {
            const int nb = cur ^ 1;
            #pragma unroll
            for (int j = 0; j < 2; j++) {
                const int row = srow0 + 32 * j;
                *(bf16x8*)&Ks[nb][row][SWZ(row, sc8)] = kreg[j];
                *(bf16x8*)&Vt[nb][row][SWZ(row, sc8)] = vreg[j];
            }
            if (tid < KB) melt[nb][tid] = 8.0f + 1.0e4f * mreg;
        }
        if (t + 2 < NTS) {
            const size_t nk = (size_t)(kt0 + (t + 2) * KB);
            #pragma unroll
            for (int j = 0; j < 2; j++) {
                kreg[j] = *(const bf16x8*)&kg[kbase + (nk + srow0 + 32 * j) * D_ + sc8 * 8];
                vreg[j] = *(const bf16x8*)&vtg[vbase + (size_t)(srow0 + 32 * j) * S_ + nk + sc8 * 8];
            }
            if (tid < KB) mreg = maskf[b * S_ + nk + tid];
        }

        #pragma unroll
        for (int kb = 0; kb < 2; kb++) {
            // ---- QK^T: st[reg] = S[key=32kb+crow(reg,hi)][q=l31] ----
            f32x16 st = {};
            __builtin_amdgcn_s_setprio(1);
            #pragma unroll
            for (int ks = 0; ks < 4; ks++) {
                const int row = 32 * kb + l31;
                bf16x8 kf = *(bf16x8*)&Ks[cur][row][SWZ(row, 2 * ks + hi)];
                st = MFMA32(kf, qf[ks], st);
            }
            __builtin_amdgcn_s_setprio(0);

            // ---- softmax: p[reg] = exp2(st - melt[key]) ----
            const float* mp = &melt[cur][32 * kb + 4 * hi];
            float4 me0 = *(const float4*)(mp);
            float4 me1 = *(const float4*)(mp + 8);
            float4 me2 = *(const float4*)(mp + 16);
            float4 me3 = *(const float4*)(mp + 24);
            float p[16];
            p[0]  = __builtin_amdgcn_exp2f(st[0]  - me0.x);
            p[1]  = __builtin_amdgcn_exp2f(st[1]  - me0.y);
            p[2]  = __builtin_amdgcn_exp2f(st[2]  - me0.z);
            p[3]  = __builtin_amdgcn_exp2f(st[3]  - me0.w);
            p[4]  = __builtin_amdgcn_exp2f(st[4]  - me1.x);
            p[5]  = __builtin_amdgcn_exp2f(st[5]  - me1.y);
            p[6]  = __builtin_amdgcn_exp2f(st[6]  - me1.z);
            p[7]  = __builtin_amdgcn_exp2f(st[7]  - me1.w);
            p[8]  = __builtin_amdgcn_exp2f(st[8]  - me2.x);
            p[9]  = __builtin_amdgcn_exp2f(st[9]  - me2.y);
            p[10] = __builtin_amdgcn_exp2f(st[10] - me2.z);
            p[11] = __builtin_amdgcn_exp2f(st[11] - me2.w);
            p[12] = __builtin_amdgcn_exp2f(st[12] - me3.x);
            p[13] = __builtin_amdgcn_exp2f(st[13] - me3.y);
            p[14] = __builtin_amdgcn_exp2f(st[14] - me3.z);
            p[15] = __builtin_amdgcn_exp2f(st[15] - me3.w);
            ps += (((p[0] + p[1]) + (p[2] + p[3])) + ((p[4] + p[5]) + (p[6] + p[7])))
                + (((p[8] + p[9]) + (p[10] + p[11])) + ((p[12] + p[13]) + (p[14] + p[15])));

            // ---- P -> bf16 PV A-frags, fully in-register ----
            unsigned x0 = pack2(p[0],  p[1]),  y0 = pack2(p[2],  p[3]);
            unsigned z0 = pack2(p[4],  p[5]),  w0 = pack2(p[6],  p[7]);
            unsigned x1 = pack2(p[8],  p[9]),  y1 = pack2(p[10], p[11]);
            unsigned z1 = pack2(p[12], p[13]), w1 = pack2(p[14], p[15]);
            const int sxx0 = sx32(x0), syy0 = sx32(y0), szz0 = sx32(z0), sww0 = sx32(w0);
            const int sxx1 = sx32(x1), syy1 = sx32(y1), szz1 = sx32(z1), sww1 = sx32(w1);
            i32x4 t0, t1;
            t0[0] = hi ? szz0 : (int)x0;
            t0[1] = hi ? sww0 : (int)y0;
            t0[2] = hi ? (int)z0 : sxx0;
            t0[3] = hi ? (int)w0 : syy0;
            t1[0] = hi ? szz1 : (int)x1;
            t1[1] = hi ? sww1 : (int)y1;
            t1[2] = hi ? (int)z1 : sxx1;
            t1[3] = hi ? (int)w1 : syy1;
            bf16x8 pa0 = __builtin_bit_cast(bf16x8, t0);   // keys 32kb+0..15 slice
            bf16x8 pa1 = __builtin_bit_cast(bf16x8, t1);   // keys 32kb+16..31 slice

            // ---- PV: oacc += P @ V ----
            const int vr0 = l31, vr1 = 32 + l31;
            bf16x8 v00 = *(bf16x8*)&Vt[cur][vr0][SWZ(vr0, 4 * kb + hi)];
            bf16x8 v01 = *(bf16x8*)&Vt[cur][vr0][SWZ(vr0, 4 * kb + 2 + hi)];
            bf16x8 v10 = *(bf16x8*)&Vt[cur][vr1][SWZ(vr1, 4 * kb + hi)];
            bf16x8 v11 = *(bf16x8*)&Vt[cur][vr1][SWZ(vr1, 4 * kb + 2 + hi)];
            __builtin_amdgcn_s_setprio(1);
            oacc0 = MFMA32(pa0, v00, oacc0);
            oacc0 = MFMA32(pa1, v01, oacc0);
            oacc1 = MFMA32(pa0, v10, oacc1);
            oacc1 = MFMA32(pa1, v11, oacc1);
            __builtin_amdgcn_s_setprio(0);
        }

        cur ^= 1;
    }

    // partial denominator for q = l31 (lane + partner half hold disjoint keys)
    const float ls = ps + __shfl_xor(ps, 32);
    if (hi == 0) {
        float* dp = dbuf + ((size_t)z * B_ * H_ + b * H_ + h) * S_;
        dp[qr0 + l31] = ls;
    }

    // raw partial numerators -> f16
    _Float16* nb2 = nbuf + (size_t)z * M_ * D_;
    #pragma unroll
    for (int reg = 0; reg < 16; reg++) {
        const int qrow = (reg & 3) + 8 * (reg >> 2) + 4 * hi;
        _Float16* np = nb2 + (size_t)(b * S_ + qr0 + qrow) * D_ + hoff;
        np[l31]      = (_Float16)oacc0[reg];
        np[32 + l31] = (_Float16)oacc1[reg];
    }
}

// ---------------------------------------------------------------------------
// Combine: ab[row][col] = bf16( (n0+n1) / (l0+l1) )
// ---------------------------------------------------------------------------
__global__ __launch_bounds__(256) void combine_kernel(const _Float16* __restrict__ nbuf,
                                                      const float* __restrict__ dbuf,
                                                      ushort_t* __restrict__ ab) {
    const int i8 = blockIdx.x * 256 + threadIdx.x;   // 8-elem chunk index
    const size_t off = (size_t)i8 * 8;
    const int row = i8 >> 7;          // D_/8 = 128 chunks per row
    const int cw  = i8 & 127;
    const int h   = cw >> 3;          // 8 chunks per head
    const int b   = row >> 11;        // row / S_
    const int s   = row & (S_ - 1);
    const size_t di = (size_t)(b * H_ + h) * S_ + s;
    const float lsum = dbuf[di] + dbuf[(size_t)B_ * H_ * S_ + di];
    const float inv = 1.f / lsum;
    f16x8 n0 = *(const f16x8*)(nbuf + off);
    f16x8 n1 = *(const f16x8*)(nbuf + (size_t)M_ * D_ + off);
    bf16x8 o;
    #pragma unroll
    for (int e = 0; e < 8; e++)
        o[e] = (short)f2bf(((float)n0[e] + (float)n1[e]) * inv);
    *(bf16x8*)(ab + off) = o;
}

// ---------------------------------------------------------------------------
// Launch. Workspace (ushort units):
//   xb[4M] mb[4M] qb[4M] kg[4M] vtg[4M] ab[4M] wqT[1M] wkT[1M] wvT[1M] woT[1M]
//   maskf f32[4096], biasKV f32[2048], dbuf f32[131072]   (~57 MB)
// xb+mb (dead after projections) are reused as nbuf[2][M_][D_] f16.
// ---------------------------------------------------------------------------
extern "C" void kernel_launch(void* const* d_in, const int* in_sizes, int n_in,
                              void* d_out, int out_size, void* d_ws, size_t ws_size,
                              hipStream_t stream) {
    const float* x      = (const float*)d_in[0];
    const float* memory = (const float*)d_in[1];
    const unsigned char* mask = (const unsigned char*)d_in[2];
    const float* wq = (const float*)d_in[3];
    const float* bq = (const float*)d_in[4];
    const float* wk = (const float*)d_in[5];
    const float* bk = (const float*)d_in[6];
    const float* wv = (const float*)d_in[7];
    const float* bv = (const float*)d_in[8];
    const float* wo = (const float*)d_in[9];
    const float* bo = (const float*)d_in[10];
    float* out = (float*)d_out;

    const size_t CH = (size_t)M_ * D_;   // 4M elements
    const size_t WH = (size_t)D_ * D_;   // 1M elements
    ushort_t* ws   = (ushort_t*)d_ws;
    ushort_t* xb   = ws;                 // nbuf after projections
    ushort_t* mb   = xb + CH;
    ushort_t* qb   = mb + CH;
    ushort_t* kg   = qb + CH;            // K: [4096][1024]
    ushort_t* vtg  = kg + CH;            // V transposed: [(b*16+h)*64+dh][2048]
    ushort_t* ab   = vtg + CH;
    ushort_t* wqT  = ab + CH;
    ushort_t* wkT  = wqT + WH;           // wkT,wvT adjacent = fused [2048][1024]
    ushort_t* wvT  = wkT + WH;
    ushort_t* woT  = wvT + WH;
    float* maskf   = (float*)(woT + WH);
    float* biasKV  = maskf + M_;
    float* dbuf    = biasKV + KSTR;
    _Float16* nbuf = (_Float16*)xb;

    prep_kernel<<<1, 256, 0, stream>>>(mask, maskf, bk, bv, biasKV);

    cvt_bf16_2<<<dim3((int)(CH / 8 / 256), 2), 256, 0, stream>>>(x, memory, xb, mb);

    transpose_cvt4<<<dim3(16, 16, 4), 256, 0, stream>>>(wq, wk, wv, wo,
                                                        wqT, wkT, wvT, woT);

    gemm_qkv<<<dim3(24, 32), 512, 0, stream>>>(xb, mb, wqT, wkT, bq, biasKV,
                                               qb, kg, vtg);

    attn_mfma<<<dim3(512, NSPLIT), 256, 0, stream>>>(qb, kg, vtg, maskf,
                                                     nbuf, dbuf);

    combine_kernel<<<(int)(CH / 8 / 256), 256, 0, stream>>>(nbuf, dbuf, ab);

    gemm_o<<<dim3(8, 32), 512, 0, stream>>>(ab, woT, bo, out);
}

// Round 13
// 166.808 us; speedup vs baseline: 1.0596x; 1.0596x over previous
//
#include <hip/hip_runtime.h>
#include <hip/hip_bf16.h>

// Problem constants
#define B_  2
#define S_  2048
#define D_  1024
#define H_  16
#define DH_ 64
#define M_  (B_*S_)   // 4096 rows
#define KSTR 2048

typedef unsigned short ushort_t;
typedef __attribute__((ext_vector_type(8)))  short bf16x8;
typedef __attribute__((ext_vector_type(4)))  float f32x4;
typedef __attribute__((ext_vector_type(16))) float f32x16;
typedef __attribute__((ext_vector_type(4)))  int   i32x4;

#define MFMA16x16(A,Bb,C) __builtin_amdgcn_mfma_f32_16x16x32_bf16(A,Bb,C,0,0,0)
#define MFMA32(A,Bb,C)    __builtin_amdgcn_mfma_f32_32x32x16_bf16(A,Bb,C,0,0,0)
#define QSCALE 0.18033688011112042f   // (1/sqrt(64)) * log2(e)

__device__ __forceinline__ ushort_t f2bf(float f) {
    return __builtin_bit_cast(ushort_t, __float2bfloat16(f));
}
__device__ __forceinline__ unsigned pack2(float a, float b) {
    return (unsigned)f2bf(a) | ((unsigned)f2bf(b) << 16);
}

// async global->LDS, 16B per lane; LDS dest = wave-uniform base + lane*16
__device__ __forceinline__ void gll16(const void* g, void* l) {
    __builtin_amdgcn_global_load_lds(
        (const __attribute__((address_space(1))) unsigned int*)g,
        (__attribute__((address_space(3))) unsigned int*)l, 16, 0, 0);
}

// chunk-XOR swizzle: 16B chunk c8 of row -> physical short offset.
#define SWZ(row, c8) ((((c8) ^ ((row) & 7))) * 8)

// ---------------------------------------------------------------------------
// Prep: mask expansion (bool8 vs int32 auto-detect) + fused KV bias build.
// ---------------------------------------------------------------------------
__global__ void prep_kernel(const unsigned char* __restrict__ mask_raw,
                            float* __restrict__ mf,
                            const float* __restrict__ bk,
                            const float* __restrict__ bv,
                            float* __restrict__ biasKV) {
    __shared__ int isBool;
    int tid = threadIdx.x;
    if (tid == 0) isBool = 0;
    __syncthreads();
    int found = 0;
    for (int i = tid; i < M_; i += 256) {
        if ((i & 3) != 0 && mask_raw[i] != 0) found = 1;
    }
    if (found) atomicOr(&isBool, 1);
    __syncthreads();
    const int isb = isBool;
    for (int i = tid; i < M_; i += 256) {
        int m;
        if (isb) m = (mask_raw[i] != 0);
        else     m = (((const int*)mask_raw)[i] != 0);
        mf[i] = m ? 1.0f : 0.0f;
    }
    for (int i = tid; i < D_; i += 256) {
        biasKV[i]      = bk[i];
        biasKV[D_ + i] = bv[i];
    }
}

// ---------------------------------------------------------------------------
// f32 -> bf16 convert, both activations in one launch
// ---------------------------------------------------------------------------
__global__ __launch_bounds__(256) void cvt_bf16_2(const float* __restrict__ x,
                                                  const float* __restrict__ mem,
                                                  ushort_t* __restrict__ xb,
                                                  ushort_t* __restrict__ mb) {
    const int i = blockIdx.x * 256 + threadIdx.x;
    const float* src = blockIdx.y ? mem : x;
    ushort_t*    dst = blockIdx.y ? mb  : xb;
    float4 a = *(const float4*)(src + (size_t)i * 8);
    float4 b = *(const float4*)(src + (size_t)i * 8 + 4);
    bf16x8 t;
    t[0] = (short)f2bf(a.x); t[1] = (short)f2bf(a.y);
    t[2] = (short)f2bf(a.z); t[3] = (short)f2bf(a.w);
    t[4] = (short)f2bf(b.x); t[5] = (short)f2bf(b.y);
    t[6] = (short)f2bf(b.z); t[7] = (short)f2bf(b.w);
    *(bf16x8*)(dst + (size_t)i * 8) = t;
}

// ---------------------------------------------------------------------------
// W[k][n] f32 -> Wt[n][k] bf16, all four weights in one launch (blockIdx.z)
// ---------------------------------------------------------------------------
__global__ __launch_bounds__(256) void transpose_cvt4(const float* __restrict__ w0,
                                                      const float* __restrict__ w1,
                                                      const float* __restrict__ w2,
                                                      const float* __restrict__ w3,
                                                      ushort_t* __restrict__ d0,
                                                      ushort_t* __restrict__ d1,
                                                      ushort_t* __restrict__ d2,
                                                      ushort_t* __restrict__ d3) {
    __shared__ ushort_t T[64][65];
    const float* W; ushort_t* Wt;
    switch (blockIdx.z) {
        case 0:  W = w0; Wt = d0; break;
        case 1:  W = w1; Wt = d1; break;
        case 2:  W = w2; Wt = d2; break;
        default: W = w3; Wt = d3; break;
    }
    const int bi = blockIdx.y;
    const int bj = blockIdx.x;
    const int tid = threadIdx.x;
    const int r = tid >> 2;
    const int c = tid & 3;

    const float* src = W + (size_t)(bi * 64 + r) * D_ + bj * 64 + c * 16;
    #pragma unroll
    for (int q = 0; q < 4; q++) {
        float4 v = *(const float4*)(src + q * 4);
        T[r][c * 16 + q * 4 + 0] = f2bf(v.x);
        T[r][c * 16 + q * 4 + 1] = f2bf(v.y);
        T[r][c * 16 + q * 4 + 2] = f2bf(v.z);
        T[r][c * 16 + q * 4 + 3] = f2bf(v.w);
    }
    __syncthreads();
    ushort_t tmp[16];
    #pragma unroll
    for (int q = 0; q < 16; q++) tmp[q] = T[c * 16 + q][r];
    ushort_t* dst = Wt + (size_t)(bj * 64 + r) * D_ + bi * 64 + c * 16;
    *(bf16x8*)(dst)     = *(bf16x8*)&tmp[0];
    *(bf16x8*)(dst + 8) = *(bf16x8*)&tmp[8];
}

// ---------------------------------------------------------------------------
// GEMM body, m97-style wave decomposition: 128x128 tile, BK=64, 256 thr =
// 4 waves (2x2), each wave owns a 64x64 sub-tile -> 32 MFMA per K-step per
// wave against 8 LDS b128 reads (4:1). Staging identical to before (gll16,
// 1024 chunks per operand, now 4 chunks/thread).
// MODE 0: f32 out rowmajor[N]; MODE 1: bf16 out rowmajor[N];
// MODE 2: bf16 out TRANSPOSED per-head -> vtg[(b*16+h)*64+dh][S_]  (V path)
// ---------------------------------------------------------------------------
template<int MODE>
__device__ __forceinline__ void gemm_body(const ushort_t* __restrict__ A,
                                          const ushort_t* __restrict__ Bt,
                                          const float* __restrict__ bias,
                                          void* __restrict__ Cv,
                                          float scale, int N, int bn,
                                          ushort_t* lds) {
    ushort_t (*As)[64] = (ushort_t(*)[64])lds;           // 128x64 = 16 KB
    ushort_t (*Bs)[64] = (ushort_t(*)[64])(lds + 8192);  // 128x64 = 16 KB

    const int tid = threadIdx.x;
    const int l15 = tid & 15;
    const int g   = (tid & 63) >> 4;
    const int w   = tid >> 6;        // 0..3
    const int wr  = w >> 1;          // 0..1 (M)
    const int wc  = w & 1;           // 0..1 (N)
    const int bm  = blockIdx.y * 128;

    f32x4 acc[4][4] = {};

    #pragma unroll 1
    for (int kt = 0; kt < D_; kt += 64) {
        __syncthreads();
        #pragma unroll
        for (int j = 0; j < 4; j++) {
            const int idx = tid + 256 * j;
            const int row = idx >> 3;
            const int c8  = idx & 7;
            gll16(A  + (size_t)(bm + row) * D_ + kt + c8 * 8,
                  (char*)&As[0][0] + idx * 16);
            gll16(Bt + (size_t)(bn + row) * D_ + kt + c8 * 8,
                  (char*)&Bs[0][0] + idx * 16);
        }
        __syncthreads();

        #pragma unroll
        for (int kk = 0; kk < 2; kk++) {
            bf16x8 a[4], b[4];
            #pragma unroll
            for (int m = 0; m < 4; m++)
                a[m] = *(bf16x8*)&As[wr * 64 + 16 * m + l15][kk * 32 + g * 8];
            #pragma unroll
            for (int n = 0; n < 4; n++)
                b[n] = *(bf16x8*)&Bs[wc * 64 + 16 * n + l15][kk * 32 + g * 8];
            #pragma unroll
            for (int m = 0; m < 4; m++)
                #pragma unroll
                for (int n = 0; n < 4; n++)
                    acc[m][n] = MFMA16x16(a[m], b[n], acc[m][n]);
        }
    }

    if (MODE != 2) {
        #pragma unroll
        for (int n = 0; n < 4; n++) {
            const int col = bn + wc * 64 + 16 * n + l15;
            const float bv = bias[col];
            #pragma unroll
            for (int m = 0; m < 4; m++) {
                #pragma unroll
                for (int r = 0; r < 4; r++) {
                    const int row = bm + wr * 64 + 16 * m + 4 * g + r;
                    const float val = (acc[m][n][r] + bv) * scale;
                    if (MODE == 1) ((ushort_t*)Cv)[(size_t)row * N + col] = f2bf(val);
                    else           ((float*)Cv)[(size_t)row * N + col] = val;
                }
            }
        }
    } else {
        // V path: transpose tile in LDS, store vtg[(b*16+h)*64+dh][s] coalesced.
        // T row stride = 136 shorts = 272 B (16B-aligned rows -> b128 reads OK).
        __syncthreads();   // done reading As/Bs
        ushort_t (*T)[136] = (ushort_t(*)[136])lds;
        #pragma unroll
        for (int n = 0; n < 4; n++) {
            const int col_l = wc * 64 + 16 * n + l15;
            const float bv = bias[bn + col_l];
            #pragma unroll
            for (int m = 0; m < 4; m++) {
                #pragma unroll
                for (int r = 0; r < 4; r++) {
                    const int row_l = wr * 64 + 16 * m + 4 * g + r;
                    T[col_l][row_l] = f2bf((acc[m][n][r] + bv) * scale);
                }
            }
        }
        __syncthreads();
        const int tc = tid >> 1;              // 0..127 (local col = output row)
        const int rc = (tid & 1) * 64;        // local row chunk (s-direction)
        const int col1 = bn + tc - 1024;      // 0..1023
        const int hh = col1 >> 6, dh = col1 & 63;
        const int bb = bm >> 11;
        const int s0 = (bm & 2047) + rc;
        ushort_t* dst = (ushort_t*)Cv + ((size_t)(bb * H_ + hh) * DH_ + dh) * S_ + s0;
        #pragma unroll
        for (int c = 0; c < 8; c++)
            *(bf16x8*)(dst + c * 8) = *(const bf16x8*)&T[tc][rc + c * 8];
    }
}

// Q + K + V projections in one dispatch: x = 0..7 -> Q, 8..15 -> K, 16..23 -> V
__global__ __launch_bounds__(256) void gemm_qkv(const ushort_t* __restrict__ xb,
                                                const ushort_t* __restrict__ mb,
                                                const ushort_t* __restrict__ wqT,
                                                const ushort_t* __restrict__ wkvT,
                                                const float* __restrict__ bq,
                                                const float* __restrict__ biasKV,
                                                ushort_t* __restrict__ qb,
                                                ushort_t* __restrict__ kg,
                                                ushort_t* __restrict__ vtg) {
    __shared__ ushort_t lds[17408];   // max(As+Bs = 16384, T = 128*136 = 17408)
    const int x = blockIdx.x;
    if (x < 8)       gemm_body<1>(xb, wqT,  bq,     qb,  QSCALE, D_, x * 128, lds);
    else if (x < 16) gemm_body<1>(mb, wkvT, biasKV, kg,  1.0f,   D_, (x - 8) * 128, lds);
    else             gemm_body<2>(mb, wkvT, biasKV, vtg, 1.0f,   KSTR, 1024 + (x - 16) * 128, lds);
}

// O projection (f32 out)
__global__ __launch_bounds__(256) void gemm_o(const ushort_t* __restrict__ ab,
                                              const ushort_t* __restrict__ woT,
                                              const float* __restrict__ bo,
                                              float* __restrict__ out) {
    __shared__ ushort_t lds[16384];
    gemm_body<0>(ab, woT, bo, out, 1.0f, D_, blockIdx.x * 128, lds);
}

// ---------------------------------------------------------------------------
// MFMA 32x32 flash attention (round-11 verified form): K+V in double-buffered
// swizzled LDS, in-register P, one barrier/tile, XCD-aware block mapping
// (bid = qt*32 + bh  =>  bid%8 = bh%8  =>  one head's q-tiles on one XCD).
// Fixed-max softmax p = exp2(s - melt[key]); masked p underflows to 0.
// ---------------------------------------------------------------------------
#define KB 64
#define NT (S_ / KB)   // 32 tiles

__device__ __forceinline__ int sx32(unsigned v) {
    return __shfl_xor((int)v, 32);
}

__global__ __launch_bounds__(256) void attn_mfma(const ushort_t* __restrict__ q,
                                                 const ushort_t* __restrict__ kg,
                                                 const ushort_t* __restrict__ vtg,
                                                 const float* __restrict__ maskf,
                                                 ushort_t* __restrict__ o) {
    __shared__ __attribute__((aligned(16))) ushort_t Ks[2][KB][64];   // 16 KB
    __shared__ __attribute__((aligned(16))) ushort_t Vt[2][DH_][64];  // 16 KB
    __shared__ float melt[2][KB];

    const int tid = threadIdx.x;
    const int w   = tid >> 6;
    const int l31 = tid & 31;
    const int hi  = (tid >> 5) & 1;

    // XCD-aware decode: blk = qt*32 + bh   (bh = b*16 + h)
    const int blk = blockIdx.x;
    const int qt  = blk >> 5;
    const int bh  = blk & 31;
    const int h   = bh & 15;
    const int b   = bh >> 4;

    const int qr0 = qt * 128 + w * 32;
    const size_t hoff  = (size_t)h * DH_;
    const size_t kbase = (size_t)(b * S_) * D_ + hoff;
    const size_t vbase = (size_t)((b * H_ + h) * DH_) * S_;

    // staging coords: 256 threads x 2 chunks; same decomposition for K and V
    const int srow0 = tid >> 3, sc8 = tid & 7;

    // Q fragments (registers): B-frag col=q=l31, k = ks*16 + hi*8 + e
    bf16x8 qf[4];
    {
        const ushort_t* qp = q + (size_t)(b * S_ + qr0 + l31) * D_ + hoff + hi * 8;
        #pragma unroll
        for (int ks = 0; ks < 4; ks++)
            qf[ks] = *(const bf16x8*)(qp + ks * 16);
    }

    f32x16 oacc0 = {}, oacc1 = {};   // O[q=crow(reg,hi)][dh = l31 / 32+l31]
    float ps = 0.f;                  // partial denominator (lane's keys only)

    bf16x8 kreg[2], vreg[2];
    float  mreg = 0.f;

    // prologue: tile 0 -> regs -> buf0; tile 1 -> regs
    #pragma unroll
    for (int j = 0; j < 2; j++) {
        kreg[j] = *(const bf16x8*)&kg[kbase + (size_t)(srow0 + 32 * j) * D_ + sc8 * 8];
        vreg[j] = *(const bf16x8*)&vtg[vbase + (size_t)(srow0 + 32 * j) * S_ + sc8 * 8];
    }
    if (tid < KB) mreg = maskf[b * S_ + tid];

    #pragma unroll
    for (int j = 0; j < 2; j++) {
        const int row = srow0 + 32 * j;
        *(bf16x8*)&Ks[0][row][SWZ(row, sc8)] = kreg[j];
        *(bf16x8*)&Vt[0][row][SWZ(row, sc8)] = vreg[j];
    }
    if (tid < KB) melt[0][tid] = 8.0f + 1.0e4f * mreg;

    #pragma unroll
    for (int j = 0; j < 2; j++) {
        kreg[j] = *(const bf16x8*)&kg[kbase + (size_t)(KB + srow0 + 32 * j) * D_ + sc8 * 8];
        vreg[j] = *(const bf16x8*)&vtg[vbase + (size_t)(srow0 + 32 * j) * S_ + KB + sc8 * 8];
    }
    if (tid < KB) mreg = maskf[b * S_ + KB + tid];

    int cur = 0;
    #pragma unroll 1
    for (int t = 0; t < NT; t++) {
        __syncthreads();   // buf[cur] ready; buf[cur^1] readers done

        if (t + 1 < NT) {
            const int nb = cur ^ 1;
            #pragma unroll
            for (int j = 0; j < 2; j++) {
                const int row = srow0 + 32 * j;
                *(bf16x8*)&Ks[nb][row][SWZ(row, sc8)] = kreg[j];
                *(bf16x8*)&Vt[nb][row][SWZ(row, sc8)] = vreg[j];
            }
            if (tid < KB) melt[nb][tid] = 8.0f + 1.0e4f * mreg;
        }
        if (t + 2 < NT) {
            const size_t nk = (size_t)(t + 2) * KB;
            #pragma unroll
            for (int j = 0; j < 2; j++) {
                kreg[j] = *(const bf16x8*)&kg[kbase + (nk + srow0 + 32 * j) * D_ + sc8 * 8];
                vreg[j] = *(const bf16x8*)&vtg[vbase + (size_t)(srow0 + 32 * j) * S_ + nk + sc8 * 8];
            }
            if (tid < KB) mreg = maskf[b * S_ + nk + tid];
        }

        #pragma unroll
        for (int kb = 0; kb < 2; kb++) {
            // ---- QK^T: st[reg] = S[key=32kb+crow(reg,hi)][q=l31] ----
            f32x16 st = {};
            __builtin_amdgcn_s_setprio(1);
            #pragma unroll
            for (int ks = 0; ks < 4; ks++) {
                const int row = 32 * kb + l31;
                bf16x8 kf = *(bf16x8*)&Ks[cur][row][SWZ(row, 2 * ks + hi)];
                st = MFMA32(kf, qf[ks], st);
            }
            __builtin_amdgcn_s_setprio(0);

            // ---- softmax: p[reg] = exp2(st - melt[key]) ----
            const float* mp = &melt[cur][32 * kb + 4 * hi];
            float4 me0 = *(const float4*)(mp);
            float4 me1 = *(const float4*)(mp + 8);
            float4 me2 = *(const float4*)(mp + 16);
            float4 me3 = *(const float4*)(mp + 24);
            float p[16];
            p[0]  = __builtin_amdgcn_exp2f(st[0]  - me0.x);
            p[1]  = __builtin_amdgcn_exp2f(st[1]  - me0.y);
            p[2]  = __builtin_amdgcn_exp2f(st[2]  - me0.z);
            p[3]  = __builtin_amdgcn_exp2f(st[3]  - me0.w);
            p[4]  = __builtin_amdgcn_exp2f(st[4]  - me1.x);
            p[5]  = __builtin_amdgcn_exp2f(st[5]  - me1.y);
            p[6]  = __builtin_amdgcn_exp2f(st[6]  - me1.z);
            p[7]  = __builtin_amdgcn_exp2f(st[7]  - me1.w);
            p[8]  = __builtin_amdgcn_exp2f(st[8]  - me2.x);
            p[9]  = __builtin_amdgcn_exp2f(st[9]  - me2.y);
            p[10] = __builtin_amdgcn_exp2f(st[10] - me2.z);
            p[11] = __builtin_amdgcn_exp2f(st[11] - me2.w);
            p[12] = __builtin_amdgcn_exp2f(st[12] - me3.x);
            p[13] = __builtin_amdgcn_exp2f(st[13] - me3.y);
            p[14] = __builtin_amdgcn_exp2f(st[14] - me3.z);
            p[15] = __builtin_amdgcn_exp2f(st[15] - me3.w);
            ps += (((p[0] + p[1]) + (p[2] + p[3])) + ((p[4] + p[5]) + (p[6] + p[7])))
                + (((p[8] + p[9]) + (p[10] + p[11])) + ((p[12] + p[13]) + (p[14] + p[15])));

            // ---- P -> bf16 PV A-frags, fully in-register ----
            unsigned x0 = pack2(p[0],  p[1]),  y0 = pack2(p[2],  p[3]);
            unsigned z0 = pack2(p[4],  p[5]),  w0 = pack2(p[6],  p[7]);
            unsigned x1 = pack2(p[8],  p[9]),  y1 = pack2(p[10], p[11]);
            unsigned z1 = pack2(p[12], p[13]), w1 = pack2(p[14], p[15]);
            const int sxx0 = sx32(x0), syy0 = sx32(y0), szz0 = sx32(z0), sww0 = sx32(w0);
            const int sxx1 = sx32(x1), syy1 = sx32(y1), szz1 = sx32(z1), sww1 = sx32(w1);
            i32x4 t0, t1;
            t0[0] = hi ? szz0 : (int)x0;
            t0[1] = hi ? sww0 : (int)y0;
            t0[2] = hi ? (int)z0 : sxx0;
            t0[3] = hi ? (int)w0 : syy0;
            t1[0] = hi ? szz1 : (int)x1;
            t1[1] = hi ? sww1 : (int)y1;
            t1[2] = hi ? (int)z1 : sxx1;
            t1[3] = hi ? (int)w1 : syy1;
            bf16x8 pa0 = __builtin_bit_cast(bf16x8, t0);   // keys 32kb+0..15 slice
            bf16x8 pa1 = __builtin_bit_cast(bf16x8, t1);   // keys 32kb+16..31 slice

            // ---- PV: oacc += P @ V ----
            const int vr0 = l31, vr1 = 32 + l31;
            bf16x8 v00 = *(bf16x8*)&Vt[cur][vr0][SWZ(vr0, 4 * kb + hi)];
            bf16x8 v01 = *(bf16x8*)&Vt[cur][vr0][SWZ(vr0, 4 * kb + 2 + hi)];
            bf16x8 v10 = *(bf16x8*)&Vt[cur][vr1][SWZ(vr1, 4 * kb + hi)];
            bf16x8 v11 = *(bf16x8*)&Vt[cur][vr1][SWZ(vr1, 4 * kb + 2 + hi)];
            __builtin_amdgcn_s_setprio(1);
            oacc0 = MFMA32(pa0, v00, oacc0);
            oacc0 = MFMA32(pa1, v01, oacc0);
            oacc1 = MFMA32(pa0, v10, oacc1);
            oacc1 = MFMA32(pa1, v11, oacc1);
            __builtin_amdgcn_s_setprio(0);
        }

        cur ^= 1;
    }

    // denominator: lane's partial + partner half (disjoint key sets)
    const float ls = ps + __shfl_xor(ps, 32);
    const float iv = 1.f / ls;   // for q = l31

    #pragma unroll
    for (int reg = 0; reg < 16; reg++) {
        const int qrow = (reg & 3) + 8 * (reg >> 2) + 4 * hi;
        const float ivr = __shfl(iv, qrow);
        ushort_t* op = o + (size_t)(b * S_ + qr0 + qrow) * D_ + hoff;
        op[l31]      = f2bf(oacc0[reg] * ivr);
        op[32 + l31] = f2bf(oacc1[reg] * ivr);
    }
}

// ---------------------------------------------------------------------------
// Launch. Workspace (ushort units):
//   xb[4M] mb[4M] qb[4M] kg[4M] vtg[4M] ab[4M] wqT[1M] wkT[1M] wvT[1M] woT[1M]
//   maskf f32[4096], biasKV f32[2048]   (~57 MB)
// ---------------------------------------------------------------------------
extern "C" void kernel_launch(void* const* d_in, const int* in_sizes, int n_in,
                              void* d_out, int out_size, void* d_ws, size_t ws_size,
                              hipStream_t stream) {
    const float* x      = (const float*)d_in[0];
    const float* memory = (const float*)d_in[1];
    const unsigned char* mask = (const unsigned char*)d_in[2];
    const float* wq = (const float*)d_in[3];
    const float* bq = (const float*)d_in[4];
    const float* wk = (const float*)d_in[5];
    const float* bk = (const float*)d_in[6];
    const float* wv = (const float*)d_in[7];
    const float* bv = (const float*)d_in[8];
    const float* wo = (const float*)d_in[9];
    const float* bo = (const float*)d_in[10];
    float* out = (float*)d_out;

    const size_t CH = (size_t)M_ * D_;   // 4M elements
    const size_t WH = (size_t)D_ * D_;   // 1M elements
    ushort_t* ws   = (ushort_t*)d_ws;
    ushort_t* xb   = ws;
    ushort_t* mb   = xb + CH;
    ushort_t* qb   = mb + CH;
    ushort_t* kg   = qb + CH;            // K: [4096][1024]
    ushort_t* vtg  = kg + CH;            // V transposed: [(b*16+h)*64+dh][2048]
    ushort_t* ab   = vtg + CH;
    ushort_t* wqT  = ab + CH;
    ushort_t* wkT  = wqT + WH;           // wkT,wvT adjacent = fused [2048][1024]
    ushort_t* wvT  = wkT + WH;
    ushort_t* woT  = wvT + WH;
    float* maskf   = (float*)(woT + WH);
    float* biasKV  = maskf + M_;

    prep_kernel<<<1, 256, 0, stream>>>(mask, maskf, bk, bv, biasKV);

    cvt_bf16_2<<<dim3((int)(CH / 8 / 256), 2), 256, 0, stream>>>(x, memory, xb, mb);

    transpose_cvt4<<<dim3(16, 16, 4), 256, 0, stream>>>(wq, wk, wv, wo,
                                                        wqT, wkT, wvT, woT);

    gemm_qkv<<<dim3(24, 32), 256, 0, stream>>>(xb, mb, wqT, wkT, bq, biasKV,
                                               qb, kg, vtg);

    attn_mfma<<<B_ * H_ * (S_ / 128), 256, 0, stream>>>(qb, kg, vtg, maskf, ab);

    gemm_o<<<dim3(8, 32), 256, 0, stream>>>(ab, woT, bo, out);
}